// Round 2
// baseline (695.364 us; speedup 1.0000x reference)
//
#include <hip/hip_runtime.h>
#include <cfloat>
#include <math.h>

// Problem constants (fixed by the reference)
#define DIM    256
#define N_TOK  8192            // 8*1024 tokens
#define N_E    8192            // codebook size
#define NCHUNK 16              // column chunks (argmin partials per row)
#define RPB    128             // rows per block (z tokens)
#define TN     128             // col tile (codes)
#define BK     32              // K-depth per LDS stage
#define PADA   1               // As leading-dim pad: 129 -> staging writes 2-way (free)
#define PADB   4               // Bs leading-dim pad: 132 -> writes 4-way, b128 reads stay 16B-aligned

// ---------------------------------------------------------------------------
// Kernel 1: row-wise L2 normalize (one wave per row, float4 per lane).
// ---------------------------------------------------------------------------
__global__ __launch_bounds__(256) void l2norm_rows(const float* __restrict__ in,
                                                   float* __restrict__ out,
                                                   float* __restrict__ nsq,
                                                   float* __restrict__ zero_me) {
    if (zero_me && blockIdx.x == 0 && threadIdx.x == 0) *zero_me = 0.0f;
    const int lane = threadIdx.x & 63;
    const int row  = (blockIdx.x << 2) + (threadIdx.x >> 6);
    const float4 v = *(const float4*)(in + row * DIM + lane * 4);
    float s = v.x * v.x + v.y * v.y + v.z * v.z + v.w * v.w;
#pragma unroll
    for (int off = 1; off < 64; off <<= 1) s += __shfl_xor(s, off, 64);
    const float inv = 1.0f / fmaxf(sqrtf(s), 1e-12f);
    const float4 o = make_float4(v.x * inv, v.y * inv, v.z * inv, v.w * inv);
    *(float4*)(out + row * DIM + lane * 4) = o;
    if (nsq) {
        float e2 = o.x * o.x + o.y * o.y + o.z * o.z + o.w * o.w;
#pragma unroll
        for (int off = 1; off < 64; off <<= 1) e2 += __shfl_xor(e2, off, 64);
        if (lane == 0) nsq[row] = e2;
    }
}

// ---------------------------------------------------------------------------
// Kernel 2: distance argmin. d(row,col) = ||e_col||^2 - 2 * <z_row, e_col>.
// 128x128 fp32 tile, 8x8 register block. LDS layout tuned for bank behavior:
//   As[BK][129]: staging writes (kq+i + r)%32 -> 2-way (free);
//                fragment reads = scalar b32 broadcast (conflict-free).
//   Bs[BK][132]: staging writes 4-way; b128 frag reads at tx*4 / tx*4+64
//                -> (4k+4tx)%32, 2-way (free), 16B-aligned.
// __launch_bounds__(256,2): allow up to 256 VGPRs (kernel needs ~110; the
// prior build capped at 76 and spilled).
// ---------------------------------------------------------------------------
__global__ __launch_bounds__(256, 2) void argmin_dist(const float* __restrict__ zn,
                                                      const float* __restrict__ en,
                                                      const float* __restrict__ e2,
                                                      float* __restrict__ pval,
                                                      int* __restrict__ pidx) {
    __shared__ float As[BK][RPB + PADA];
    __shared__ __align__(16) float Bs[BK][TN + PADB];

    const int tid = threadIdx.x;
    const int tx = tid & 15;        // col group
    const int ty = tid >> 4;        // row group (8 rows each)
    const int rowBlk = blockIdx.x & 63;
    const int chunk  = blockIdx.x >> 6;
    const int row0 = rowBlk * RPB;
    const int col0 = chunk * (N_E / NCHUNK);

    float minv[8];
    int   mini[8];
#pragma unroll
    for (int r = 0; r < 8; r++) { minv[r] = FLT_MAX; mini[r] = 0x7fffffff; }

    for (int ct = 0; ct < (N_E / NCHUNK) / TN; ct++) {   // 4 col tiles
        const int colbase = col0 + ct * TN;
        float acc[8][8];
#pragma unroll
        for (int r = 0; r < 8; r++)
#pragma unroll
            for (int c = 0; c < 8; c++) acc[r][c] = 0.0f;

        for (int kc = 0; kc < DIM / BK; kc++) {          // 8 K stages
            const int k0 = kc * BK;
            // Stage 128x32 A and B tiles, transposing to k-major on the fly.
#pragma unroll
            for (int j = 0; j < 4; j++) {
                const int f  = tid + j * 256;            // float4 id in [0,1024)
                const int r  = f >> 3;                   // tile row/col [0,128)
                const int kq = (f & 7) << 2;             // k offset 0,4,...,28
                const float4 a = *(const float4*)(zn + (row0 + r) * DIM + k0 + kq);
                As[kq + 0][r] = a.x; As[kq + 1][r] = a.y;
                As[kq + 2][r] = a.z; As[kq + 3][r] = a.w;
                const float4 b = *(const float4*)(en + (colbase + r) * DIM + k0 + kq);
                Bs[kq + 0][r] = b.x; Bs[kq + 1][r] = b.y;
                Bs[kq + 2][r] = b.z; Bs[kq + 3][r] = b.w;
            }
            __syncthreads();
#pragma unroll 8
            for (int k = 0; k < BK; k++) {
                float a[8];
#pragma unroll
                for (int j = 0; j < 8; j++) a[j] = As[k][ty * 8 + j];  // broadcast b32
                const float4 b0 = *(const float4*)&Bs[k][tx * 4];
                const float4 b1 = *(const float4*)&Bs[k][tx * 4 + 64];
                const float b[8] = {b0.x, b0.y, b0.z, b0.w, b1.x, b1.y, b1.z, b1.w};
#pragma unroll
                for (int r = 0; r < 8; r++)
#pragma unroll
                    for (int c = 0; c < 8; c++)
                        acc[r][c] = fmaf(a[r], b[c], acc[r][c]);
            }
            __syncthreads();
        }
        // Epilogue: distance + running argmin. Thread covers cols
        // colbase+tx*4+{0..3} and colbase+64+tx*4+{0..3}; iterate ascending
        // so strict '<' keeps first occurrence (jnp.argmin tie-break).
#pragma unroll
        for (int c = 0; c < 8; c++) {
            const int col = colbase + ((c < 4) ? (tx * 4 + c) : (64 + tx * 4 + c - 4));
            const float d2 = e2[col];
#pragma unroll
            for (int r = 0; r < 8; r++) {
                const float d = fmaf(-2.0f, acc[r][c], d2);
                if (d < minv[r]) { minv[r] = d; mini[r] = col; }
            }
        }
    }
    // Reduce across the 16 col-thread-groups (xor on low 4 bits stays in-group).
#pragma unroll
    for (int off = 1; off < 16; off <<= 1) {
#pragma unroll
        for (int r = 0; r < 8; r++) {
            const float ov = __shfl_xor(minv[r], off, 64);
            const int   oi = __shfl_xor(mini[r], off, 64);
            if (ov < minv[r] || (ov == minv[r] && oi < mini[r])) {
                minv[r] = ov; mini[r] = oi;
            }
        }
    }
    if (tx == 0) {
#pragma unroll
        for (int r = 0; r < 8; r++) {
            const int row = row0 + ty * 8 + r;
            pval[row * NCHUNK + chunk] = minv[r];
            pidx[row * NCHUNK + chunk] = mini[r];
        }
    }
}

// ---------------------------------------------------------------------------
// Kernel 3: merge the 16 partials per row, gather normalized code (== z_q),
// overwrite z_norm with z_q in d_out, accumulate sum((z_q - z)^2), emit index.
// ---------------------------------------------------------------------------
__global__ __launch_bounds__(256) void merge_gather(const float* __restrict__ pval,
                                                    const int* __restrict__ pidx,
                                                    const float* __restrict__ en,
                                                    float* zqz,      // z_norm in / z_q out (d_out)
                                                    float* out_base, // d_out (for idx slot)
                                                    float* ws_loss) {
    const int lane = threadIdx.x & 63;
    const int row  = (blockIdx.x << 2) + (threadIdx.x >> 6);
    float v = pval[row * NCHUNK + (lane & 15)];
    int   i = pidx[row * NCHUNK + (lane & 15)];
#pragma unroll
    for (int off = 1; off < 16; off <<= 1) {
        const float ov = __shfl_xor(v, off, 64);
        const int   oi = __shfl_xor(i, off, 64);
        if (ov < v || (ov == v && oi < i)) { v = ov; i = oi; }
    }
    const float4 q = *(const float4*)(en + i * DIM + lane * 4);
    const float4 z = *(const float4*)(zqz + row * DIM + lane * 4);
    const float dx = q.x - z.x, dy = q.y - z.y, dz = q.z - z.z, dw = q.w - z.w;
    float s = dx * dx + dy * dy + dz * dz + dw * dw;
    *(float4*)(zqz + row * DIM + lane * 4) = q;   // straight-through value == z_q
#pragma unroll
    for (int off = 1; off < 64; off <<= 1) s += __shfl_xor(s, off, 64);
    if (lane == 0) {
        atomicAdd(ws_loss, s);
        out_base[N_TOK * DIM + 1 + row] = (float)i;  // indices as float32
    }
}

// ---------------------------------------------------------------------------
// Kernel 4: loss = 1.25 * sum / (8*1024*256)
// ---------------------------------------------------------------------------
__global__ void finalize_loss(const float* __restrict__ ws_loss, float* __restrict__ out) {
    out[N_TOK * DIM] = *ws_loss * (1.25f / 2097152.0f);
}

// ---------------------------------------------------------------------------
extern "C" void kernel_launch(void* const* d_in, const int* in_sizes, int n_in,
                              void* d_out, int out_size, void* d_ws, size_t ws_size,
                              hipStream_t stream) {
    const float* z   = (const float*)d_in[0];   // [8,1024,256] fp32
    const float* emb = (const float*)d_in[1];   // [8192,256] fp32
    float* out = (float*)d_out;                 // z_q[2097152] | loss[1] | idx[8192]
    char* ws = (char*)d_ws;

    // ws layout (bytes): en 8 MiB | e2 32 KiB | pval 512 KiB | pidx 512 KiB | loss 4 B
    float* en   = (float*)(ws);
    float* e2   = (float*)(ws + 8388608);
    float* pval = (float*)(ws + 8421376);
    int*   pidx = (int*)  (ws + 8945664);
    float* wl   = (float*)(ws + 9469952);

    // 1) normalize embeddings -> ws (+ ||e||^2, zero loss accumulator)
    l2norm_rows<<<N_E / 4, 256, 0, stream>>>(emb, en, e2, wl);
    // 2) normalize z -> d_out's z_q region (scratch until merge_gather)
    l2norm_rows<<<N_TOK / 4, 256, 0, stream>>>(z, out, nullptr, nullptr);
    // 3) distance + per-chunk argmin partials
    argmin_dist<<<64 * NCHUNK, 256, 0, stream>>>(out, en, e2, pval, pidx);
    // 4) merge partials, gather z_q, loss partial sums, write indices
    merge_gather<<<N_TOK / 4, 256, 0, stream>>>(pval, pidx, en, out, out, wl);
    // 5) scale loss
    finalize_loss<<<1, 1, 0, stream>>>(wl, out);
}

// Round 3
// 566.563 us; speedup vs baseline: 1.2273x; 1.2273x over previous
//
#include <hip/hip_runtime.h>
#include <cfloat>
#include <math.h>

// Problem constants (fixed by the reference)
#define DIM    256
#define N_TOK  8192
#define N_E    8192
#define NSEG   128          // 64-col segments per row
#define MARGIN 0.032f       // > rigorous 2*Delta bound (Delta=2^-6=0.0156 on d)
#define CAP    131072       // rescore-list capacity (expected ~12k entries)

typedef __attribute__((ext_vector_type(8))) short bf16x8;
typedef __attribute__((ext_vector_type(4))) float f32x4;

__device__ __forceinline__ unsigned short f2bf(float f) {      // RNE float->bf16
    unsigned u = __float_as_uint(f);
    unsigned r = u + 0x7fff + ((u >> 16) & 1);
    return (unsigned short)(r >> 16);
}
__device__ __forceinline__ unsigned fkey(float f) {            // monotone f32->u32
    unsigned u = __float_as_uint(f);
    return (u & 0x80000000u) ? ~u : (u | 0x80000000u);
}

// ---------------------------------------------------------------------------
// K1/K2: row-wise L2 normalize -> fp32 out + bf16 out. Optionally ||out||^2
// per row and zeroing of the loss/cnt accumulators (ws is re-poisoned 0xAA).
// ---------------------------------------------------------------------------
__global__ __launch_bounds__(256) void l2norm_rows(const float* __restrict__ in,
                                                   float* __restrict__ out,
                                                   unsigned short* __restrict__ outb,
                                                   float* __restrict__ nsq,
                                                   float* __restrict__ zf,
                                                   int* __restrict__ zi) {
    if (zf && blockIdx.x == 0 && threadIdx.x == 0) { *zf = 0.0f; *zi = 0; }
    const int lane = threadIdx.x & 63;
    const int row  = (blockIdx.x << 2) + (threadIdx.x >> 6);
    const float4 v = *(const float4*)(in + row * DIM + lane * 4);
    float s = v.x * v.x + v.y * v.y + v.z * v.z + v.w * v.w;
#pragma unroll
    for (int off = 1; off < 64; off <<= 1) s += __shfl_xor(s, off, 64);
    const float inv = 1.0f / fmaxf(sqrtf(s), 1e-12f);
    const float4 o = make_float4(v.x * inv, v.y * inv, v.z * inv, v.w * inv);
    *(float4*)(out + row * DIM + lane * 4) = o;
    ushort4 ob; ob.x = f2bf(o.x); ob.y = f2bf(o.y); ob.z = f2bf(o.z); ob.w = f2bf(o.w);
    *(ushort4*)(outb + row * DIM + lane * 4) = ob;
    if (nsq) {
        float e2 = o.x * o.x + o.y * o.y + o.z * o.z + o.w * o.w;
#pragma unroll
        for (int off = 1; off < 64; off <<= 1) e2 += __shfl_xor(e2, off, 64);
        if (lane == 0) nsq[row] = e2;
    }
}

// ---------------------------------------------------------------------------
// K3: bf16 MFMA distance pass (m97 recipe). 128x128 block tile, 4 waves of
// 64x64 (4x4 grid of 16x16x32 MFMAs), BK=32, global_load_lds width=16.
// Epilogue: per (row, wave's 64-col segment) min of d~ = e2[col] - 2*dot.
// No indices kept — exact rescoring decides the argmin.
// ---------------------------------------------------------------------------
__global__ __launch_bounds__(256, 2) void mfma_dist(const unsigned short* __restrict__ zb,
                                                    const unsigned short* __restrict__ eb,
                                                    const float* __restrict__ e2,
                                                    float* __restrict__ segMin) {
    __shared__ __align__(16) unsigned short As[128][32];   // [row][k] bf16, 8 KB
    __shared__ __align__(16) unsigned short Bs[128][32];

    const int tid  = threadIdx.x;
    const int lane = tid & 63;
    const int wave = tid >> 6;
    const int wm = wave & 1, wn = wave >> 1;
    const int row0 = (blockIdx.x & 63) * 128;
    const int col0 = (blockIdx.x >> 6) * 128;

    f32x4 acc[4][4];
#pragma unroll
    for (int mi = 0; mi < 4; mi++)
#pragma unroll
        for (int ni = 0; ni < 4; ni++) acc[mi][ni] = (f32x4){0.f, 0.f, 0.f, 0.f};

    // Staging map: lane i -> row wave*32 + j*16 + i/4, k-chunk (i%4)*8.
    // LDS dest = uniform base + lane*16B, matching [row][k] row-major exactly.
    const int srow  = lane >> 2;
    const int skoff = (lane & 3) * 8;
    const unsigned short* gA = zb + (row0 + wave * 32 + srow) * DIM + skoff;
    const unsigned short* gB = eb + (col0 + wave * 32 + srow) * DIM + skoff;

    for (int kc = 0; kc < DIM / 32; kc++) {
        __syncthreads();                       // readers of previous tile done
#pragma unroll
        for (int j = 0; j < 2; j++) {
            __builtin_amdgcn_global_load_lds(
                (const __attribute__((address_space(1))) unsigned int*)(gA + j * 16 * DIM + kc * 32),
                (__attribute__((address_space(3))) unsigned int*)&As[wave * 32 + j * 16][0],
                16, 0, 0);
            __builtin_amdgcn_global_load_lds(
                (const __attribute__((address_space(1))) unsigned int*)(gB + j * 16 * DIM + kc * 32),
                (__attribute__((address_space(3))) unsigned int*)&Bs[wave * 32 + j * 16][0],
                16, 0, 0);
        }
        __syncthreads();                       // staging drained (vmcnt(0) @ barrier)
        const int fr = lane & 15, q = lane >> 4;
        bf16x8 af[4], bfr[4];
#pragma unroll
        for (int i = 0; i < 4; i++) af[i]  = *(const bf16x8*)&As[wm * 64 + i * 16 + fr][q * 8];
#pragma unroll
        for (int i = 0; i < 4; i++) bfr[i] = *(const bf16x8*)&Bs[wn * 64 + i * 16 + fr][q * 8];
#pragma unroll
        for (int mi = 0; mi < 4; mi++)
#pragma unroll
            for (int ni = 0; ni < 4; ni++)
                acc[mi][ni] = __builtin_amdgcn_mfma_f32_16x16x32_bf16(af[mi], bfr[ni], acc[mi][ni], 0, 0, 0);
    }

    // Epilogue. C/D layout: col = lane&15, row = (lane>>4)*4 + reg.
    const int fr = lane & 15, q = lane >> 4;
    float e2v[4];
#pragma unroll
    for (int ni = 0; ni < 4; ni++) e2v[ni] = e2[col0 + wn * 64 + ni * 16 + fr];
    const int seg = (blockIdx.x >> 6) * 2 + wn;
#pragma unroll
    for (int mi = 0; mi < 4; mi++) {
#pragma unroll
        for (int r = 0; r < 4; r++) {
            float m = fmaf(-2.0f, acc[mi][0][r], e2v[0]);
#pragma unroll
            for (int ni = 1; ni < 4; ni++)
                m = fminf(m, fmaf(-2.0f, acc[mi][ni][r], e2v[ni]));
#pragma unroll
            for (int off = 1; off < 16; off <<= 1) m = fminf(m, __shfl_xor(m, off, 64));
            if (fr == 0)
                segMin[(row0 + wm * 64 + mi * 16 + q * 4 + r) * NSEG + seg] = m;
        }
    }
}

// ---------------------------------------------------------------------------
// K4: per row: m = min over 128 segment-mins; flag segments within m+MARGIN
// (winner always self-flags); append (row,seg) entries; init rowres.
// ---------------------------------------------------------------------------
__global__ __launch_bounds__(256) void merge_flag(const float* __restrict__ segMin,
                                                  unsigned long long* __restrict__ rowres,
                                                  unsigned long long* __restrict__ list,
                                                  int* __restrict__ cnt) {
    const int lane = threadIdx.x & 63;
    const int row  = (blockIdx.x << 2) + (threadIdx.x >> 6);
    const float a0 = segMin[row * NSEG + lane];
    const float a1 = segMin[row * NSEG + 64 + lane];
    float m = fminf(a0, a1);
#pragma unroll
    for (int off = 1; off < 64; off <<= 1) m = fminf(m, __shfl_xor(m, off, 64));
    const float thr = m + MARGIN;
    if (lane == 0) rowres[row] = ~0ull;
    const bool f0 = (a0 <= thr), f1 = (a1 <= thr);
    const unsigned long long b0 = __ballot(f0), b1 = __ballot(f1);
    const int n0 = __popcll(b0);
    int base = 0;
    if (lane == 0) base = atomicAdd(cnt, n0 + __popcll(b1));
    base = __shfl(base, 0, 64);
    const unsigned long long below = (1ull << lane) - 1;
    if (f0) {
        const int s = base + __popcll(b0 & below);
        if (s < CAP) list[s] = ((unsigned long long)row << 32) | (unsigned)lane;
    }
    if (f1) {
        const int s = base + n0 + __popcll(b1 & below);
        if (s < CAP) list[s] = ((unsigned long long)row << 32) | (unsigned)(64 + lane);
    }
}

// ---------------------------------------------------------------------------
// K5: exact fp32 rescore. One wave per (row,seg): lane handles one col,
// full 256-d fp32 dot, packed (sortable dist | col) u64 atomicMin per row
// -> exact argmin with lowest-index tie-break.
// ---------------------------------------------------------------------------
__global__ __launch_bounds__(256) void rescore(const unsigned long long* __restrict__ list,
                                               const int* __restrict__ cnt,
                                               const float* __restrict__ zn,
                                               const float* __restrict__ en,
                                               const float* __restrict__ e2,
                                               unsigned long long* __restrict__ rowres) {
    const int lane = threadIdx.x & 63;
    const int w = (int)((blockIdx.x * blockDim.x + threadIdx.x) >> 6);
    const int W = (int)((gridDim.x * blockDim.x) >> 6);
    const int n = min(*cnt, (int)CAP);
    for (int i = w; i < n; i += W) {
        const unsigned long long ent = list[i];
        const int row = (int)(ent >> 32);
        const int col = ((int)(ent & 0xffffffffu)) * 64 + lane;
        const float4* zp = (const float4*)(zn + row * DIM);
        const float4* ep = (const float4*)(en + col * DIM);
        float s0 = 0.f, s1 = 0.f, s2 = 0.f, s3 = 0.f;
#pragma unroll 16
        for (int j = 0; j < DIM / 4; j++) {
            const float4 zv = zp[j], ev = ep[j];
            s0 = fmaf(zv.x, ev.x, s0); s1 = fmaf(zv.y, ev.y, s1);
            s2 = fmaf(zv.z, ev.z, s2); s3 = fmaf(zv.w, ev.w, s3);
        }
        const float d = fmaf(-2.0f, (s0 + s1) + (s2 + s3), e2[col]);
        unsigned long long pk = ((unsigned long long)fkey(d) << 32) | (unsigned)col;
#pragma unroll
        for (int off = 1; off < 64; off <<= 1) {
            const unsigned long long o = __shfl_xor(pk, off, 64);
            if (o < pk) pk = o;
        }
        if (lane == 0) atomicMin(&rowres[row], pk);
    }
}

// ---------------------------------------------------------------------------
// K6: gather z_q = en[idx], loss partials, indices (as float).
// ---------------------------------------------------------------------------
__global__ __launch_bounds__(256) void gather_out(const unsigned long long* __restrict__ rowres,
                                                  const float* __restrict__ en,
                                                  float* zqz,       // z_norm in / z_q out (d_out)
                                                  float* out_base,  // d_out
                                                  float* ws_loss) {
    const int lane = threadIdx.x & 63;
    const int row  = (blockIdx.x << 2) + (threadIdx.x >> 6);
    const int i = (int)(rowres[row] & 0xffffffffu);
    const float4 qv = *(const float4*)(en + i * DIM + lane * 4);
    const float4 zv = *(const float4*)(zqz + row * DIM + lane * 4);
    const float dx = qv.x - zv.x, dy = qv.y - zv.y, dz = qv.z - zv.z, dw = qv.w - zv.w;
    float s = dx * dx + dy * dy + dz * dz + dw * dw;
    *(float4*)(zqz + row * DIM + lane * 4) = qv;
#pragma unroll
    for (int off = 1; off < 64; off <<= 1) s += __shfl_xor(s, off, 64);
    if (lane == 0) {
        atomicAdd(ws_loss, s);
        out_base[N_TOK * DIM + 1 + row] = (float)i;
    }
}

__global__ void finalize_loss(const float* __restrict__ ws_loss, float* __restrict__ out) {
    out[N_TOK * DIM] = *ws_loss * (1.25f / 2097152.0f);
}

// ---------------------------------------------------------------------------
extern "C" void kernel_launch(void* const* d_in, const int* in_sizes, int n_in,
                              void* d_out, int out_size, void* d_ws, size_t ws_size,
                              hipStream_t stream) {
    const float* z   = (const float*)d_in[0];   // [8,1024,256] fp32
    const float* emb = (const float*)d_in[1];   // [8192,256] fp32
    float* out = (float*)d_out;                 // z_q[2097152] | loss[1] | idx[8192]
    char* ws = (char*)d_ws;

    // ws layout (byte offsets; total ~22.2 MB)
    float*              en     = (float*)(ws);                          //  8 MiB fp32 codes (normalized)
    unsigned short*     eb     = (unsigned short*)(ws + 8388608);       //  4 MiB bf16 codes
    unsigned short*     zb     = (unsigned short*)(ws + 12582912);      //  4 MiB bf16 z
    float*              e2     = (float*)(ws + 16777216);               // 32 KiB ||e||^2
    float*              segMin = (float*)(ws + 16809984);               //  4 MiB [8192][128]
    unsigned long long* rowres = (unsigned long long*)(ws + 21004288);  // 64 KiB packed results
    unsigned long long* list   = (unsigned long long*)(ws + 21069824);  //  1 MiB rescore list
    int*                cnt    = (int*)(ws + 22118400);
    float*              wl     = (float*)(ws + 22118408);

    // 1) normalize embeddings -> en fp32 + eb bf16 + e2; zero wl/cnt
    l2norm_rows<<<N_E / 4, 256, 0, stream>>>(emb, en, eb, e2, wl, cnt);
    // 2) normalize z -> d_out z_q region (fp32 scratch) + zb bf16
    l2norm_rows<<<N_TOK / 4, 256, 0, stream>>>(z, out, zb, nullptr, nullptr, nullptr);
    // 3) bf16 MFMA approx distances -> per-(row,segment) min
    mfma_dist<<<64 * 64, 256, 0, stream>>>(zb, eb, e2, segMin);
    // 4) per-row merge + margin flags -> rescore list; init rowres
    merge_flag<<<N_TOK / 4, 256, 0, stream>>>(segMin, rowres, list, cnt);
    // 5) exact fp32 rescore of flagged segments -> packed argmin per row
    rescore<<<1024, 256, 0, stream>>>(list, cnt, out, en, e2, rowres);
    // 6) gather z_q, loss partials, indices
    gather_out<<<N_TOK / 4, 256, 0, stream>>>(rowres, en, out, out, wl);
    // 7) scale loss
    finalize_loss<<<1, 1, 0, stream>>>(wl, out);
}

// Round 4
// 462.502 us; speedup vs baseline: 1.5035x; 1.2250x over previous
//
#include <hip/hip_runtime.h>
#include <cfloat>
#include <math.h>

// Problem constants (fixed by the reference)
#define DIM    256
#define N_TOK  8192
#define N_E    8192
#define NSEG   512          // 16-col groups per row
// Margin on d = ||e||^2 - 2*dot. Rigorous worst-case bf16 bound is 0.0312,
// but actual RNE error is a 512-term random sum: std(dd)~2e-4, max over 67M
// pairs ~1.1e-3. 0.016 = 7x the 2*max comparison requirement.
#define MARGIN 0.016f
#define CAP    131072       // rescore-list capacity (expected ~14k entries)

typedef __attribute__((ext_vector_type(8))) short bf16x8;
typedef __attribute__((ext_vector_type(4))) float f32x4;

__device__ __forceinline__ unsigned short f2bf(float f) {      // RNE float->bf16
    unsigned u = __float_as_uint(f);
    unsigned r = u + 0x7fff + ((u >> 16) & 1);
    return (unsigned short)(r >> 16);
}
__device__ __forceinline__ unsigned fkey(float f) {            // monotone f32->u32
    unsigned u = __float_as_uint(f);
    return (u & 0x80000000u) ? ~u : (u | 0x80000000u);
}

// ---------------------------------------------------------------------------
// K1/K2: row-wise L2 normalize -> fp32 out + bf16 out. Optionally ||out||^2
// per row and zeroing of the loss/cnt accumulators (ws is re-poisoned 0xAA).
// ---------------------------------------------------------------------------
__global__ __launch_bounds__(256) void l2norm_rows(const float* __restrict__ in,
                                                   float* __restrict__ out,
                                                   unsigned short* __restrict__ outb,
                                                   float* __restrict__ nsq,
                                                   float* __restrict__ zf,
                                                   int* __restrict__ zi) {
    if (zf && blockIdx.x == 0 && threadIdx.x == 0) { *zf = 0.0f; *zi = 0; }
    const int lane = threadIdx.x & 63;
    const int row  = (blockIdx.x << 2) + (threadIdx.x >> 6);
    const float4 v = *(const float4*)(in + row * DIM + lane * 4);
    float s = v.x * v.x + v.y * v.y + v.z * v.z + v.w * v.w;
#pragma unroll
    for (int off = 1; off < 64; off <<= 1) s += __shfl_xor(s, off, 64);
    const float inv = 1.0f / fmaxf(sqrtf(s), 1e-12f);
    const float4 o = make_float4(v.x * inv, v.y * inv, v.z * inv, v.w * inv);
    *(float4*)(out + row * DIM + lane * 4) = o;
    ushort4 ob; ob.x = f2bf(o.x); ob.y = f2bf(o.y); ob.z = f2bf(o.z); ob.w = f2bf(o.w);
    *(ushort4*)(outb + row * DIM + lane * 4) = ob;
    if (nsq) {
        float e2 = o.x * o.x + o.y * o.y + o.z * o.z + o.w * o.w;
#pragma unroll
        for (int off = 1; off < 64; off <<= 1) e2 += __shfl_xor(e2, off, 64);
        if (lane == 0) nsq[row] = e2;
    }
}

// ---------------------------------------------------------------------------
// K3: bf16 MFMA distance pass. 128x128 block tile, 4 waves of 64x64 (4x4 grid
// of 16x16x32 MFMAs), BK=32, global_load_lds width=16.
// Epilogue: per (row, 16-col group) min of d~ = e2[col] - 2*dot, funneled
// through LDS and written TRANSPOSED (segT[seg][row]) fully coalesced.
// ---------------------------------------------------------------------------
__global__ __launch_bounds__(256, 2) void mfma_dist(const unsigned short* __restrict__ zb,
                                                    const unsigned short* __restrict__ eb,
                                                    const float* __restrict__ e2,
                                                    float* __restrict__ segT) {
    __shared__ __align__(16) unsigned short As[128][32];   // [row][k] bf16, 8 KB
    __shared__ __align__(16) unsigned short Bs[128][32];
    __shared__ __align__(16) float sm[8][128];             // [seg_local][row_local]

    const int tid  = threadIdx.x;
    const int lane = tid & 63;
    const int wave = tid >> 6;
    const int wm = wave & 1, wn = wave >> 1;
    const int row0 = (blockIdx.x & 63) * 128;
    const int col0 = (blockIdx.x >> 6) * 128;

    f32x4 acc[4][4];
#pragma unroll
    for (int mi = 0; mi < 4; mi++)
#pragma unroll
        for (int ni = 0; ni < 4; ni++) acc[mi][ni] = (f32x4){0.f, 0.f, 0.f, 0.f};

    // Staging map: lane i -> row wave*32 + i/4, k-chunk (i%4)*8 (16B).
    const int srow  = lane >> 2;
    const int skoff = (lane & 3) * 8;
    const unsigned short* gA = zb + (row0 + wave * 32 + srow) * DIM + skoff;
    const unsigned short* gB = eb + (col0 + wave * 32 + srow) * DIM + skoff;

    for (int kc = 0; kc < DIM / 32; kc++) {
        __syncthreads();                       // readers of previous tile done
#pragma unroll
        for (int j = 0; j < 2; j++) {
            __builtin_amdgcn_global_load_lds(
                (const __attribute__((address_space(1))) unsigned int*)(gA + j * 16 * DIM + kc * 32),
                (__attribute__((address_space(3))) unsigned int*)&As[wave * 32 + j * 16][0],
                16, 0, 0);
            __builtin_amdgcn_global_load_lds(
                (const __attribute__((address_space(1))) unsigned int*)(gB + j * 16 * DIM + kc * 32),
                (__attribute__((address_space(3))) unsigned int*)&Bs[wave * 32 + j * 16][0],
                16, 0, 0);
        }
        __syncthreads();                       // staging drained (vmcnt(0) @ barrier)
        const int fr = lane & 15, q = lane >> 4;
        bf16x8 af[4], bfr[4];
#pragma unroll
        for (int i = 0; i < 4; i++) af[i]  = *(const bf16x8*)&As[wm * 64 + i * 16 + fr][q * 8];
#pragma unroll
        for (int i = 0; i < 4; i++) bfr[i] = *(const bf16x8*)&Bs[wn * 64 + i * 16 + fr][q * 8];
#pragma unroll
        for (int mi = 0; mi < 4; mi++)
#pragma unroll
            for (int ni = 0; ni < 4; ni++)
                acc[mi][ni] = __builtin_amdgcn_mfma_f32_16x16x32_bf16(af[mi], bfr[ni], acc[mi][ni], 0, 0, 0);
    }

    // Epilogue. C/D layout: col = lane&15, row = (lane>>4)*4 + reg.
    const int fr = lane & 15, q = lane >> 4;
    float e2v[4];
#pragma unroll
    for (int ni = 0; ni < 4; ni++) e2v[ni] = e2[col0 + wn * 64 + ni * 16 + fr];
#pragma unroll
    for (int mi = 0; mi < 4; mi++) {
#pragma unroll
        for (int ni = 0; ni < 4; ni++) {
            float m0 = fmaf(-2.0f, acc[mi][ni][0], e2v[ni]);
            float m1 = fmaf(-2.0f, acc[mi][ni][1], e2v[ni]);
            float m2 = fmaf(-2.0f, acc[mi][ni][2], e2v[ni]);
            float m3 = fmaf(-2.0f, acc[mi][ni][3], e2v[ni]);
#pragma unroll
            for (int off = 1; off < 16; off <<= 1) {   // min over the 16 cols (fr lanes)
                m0 = fminf(m0, __shfl_xor(m0, off, 64));
                m1 = fminf(m1, __shfl_xor(m1, off, 64));
                m2 = fminf(m2, __shfl_xor(m2, off, 64));
                m3 = fminf(m3, __shfl_xor(m3, off, 64));
            }
            if (fr == 0) {   // 4 lanes (q=0..3), rows q*4+r consecutive -> b128
                *(float4*)&sm[wn * 4 + ni][wm * 64 + mi * 16 + q * 4] =
                    make_float4(m0, m1, m2, m3);
            }
        }
    }
    __syncthreads();
    // Cooperative coalesced store: 8 segs x 128 rows, transposed layout.
#pragma unroll
    for (int it = 0; it < 4; it++) {
        const int idx = tid + it * 256;            // 0..1023
        const int sl = idx >> 7, rl = idx & 127;
        segT[((blockIdx.x >> 6) * 8 + sl) * N_TOK + row0 + rl] = sm[sl][rl];
    }
}

// ---------------------------------------------------------------------------
// K4: per row: m = min over 512 group-mins; flag groups within m+MARGIN
// (winner's group always self-flags); append packed (row<<9|seg) entries.
// segT is [seg][row] -> threads (rows) read coalesced at each seg step.
// ---------------------------------------------------------------------------
__global__ __launch_bounds__(256) void merge_flag(const float* __restrict__ segT,
                                                  unsigned long long* __restrict__ rowres,
                                                  unsigned* __restrict__ list,
                                                  int* __restrict__ cnt) {
    __shared__ float sm2[2][128];
    const int t = threadIdx.x, half = t >> 7, r = t & 127;
    const int row = (blockIdx.x << 7) + r;
    const float* p = segT + (size_t)(half * 256) * N_TOK + row;
    float m = FLT_MAX;
#pragma unroll 8
    for (int s = 0; s < 256; s++) m = fminf(m, p[(size_t)s * N_TOK]);
    sm2[half][r] = m;
    if (half == 0) rowres[row] = ~0ull;
    __syncthreads();
    const float thr = fminf(sm2[0][r], sm2[1][r]) + MARGIN;
#pragma unroll 4
    for (int s = 0; s < 256; s++) {
        if (p[(size_t)s * N_TOK] <= thr) {
            const int pos = atomicAdd(cnt, 1);
            if (pos < CAP) list[pos] = (unsigned)((row << 9) | (half * 256 + s));
        }
    }
}

// ---------------------------------------------------------------------------
// K5: exact fp32 rescore. One wave per (row, 16-col group): 4 passes of
// 4 cols; 16 lanes split the 256-dim fp32 dot (coalesced 1KB rows). Packed
// (sortable dist | col) u64 atomicMin per row -> exact argmin, lowest-index
// tie-break (matches jnp.argmin).
// ---------------------------------------------------------------------------
__global__ __launch_bounds__(256) void rescore(const unsigned* __restrict__ list,
                                               const int* __restrict__ cnt,
                                               const float* __restrict__ zn,
                                               const float* __restrict__ en,
                                               const float* __restrict__ e2,
                                               unsigned long long* __restrict__ rowres) {
    const int lane = threadIdx.x & 63;
    const int q = lane >> 4, f = lane & 15;
    const int w = (int)((blockIdx.x * blockDim.x + threadIdx.x) >> 6);
    const int W = (int)((gridDim.x * blockDim.x) >> 6);
    const int n = min(*cnt, (int)CAP);
    for (int i = w; i < n; i += W) {
        const unsigned ent = list[i];
        const int row = (int)(ent >> 9);
        const int seg = (int)(ent & 511u);
        const float4* zp = (const float4*)(zn + row * DIM);
        float4 z4[4];
#pragma unroll
        for (int j = 0; j < 4; j++) z4[j] = zp[j * 16 + f];
        unsigned long long pk = ~0ull;
#pragma unroll
        for (int g = 0; g < 4; g++) {
            const int col = seg * 16 + g * 4 + q;
            const float4* ep = (const float4*)(en + col * DIM);
            float s = 0.f;
#pragma unroll
            for (int j = 0; j < 4; j++) {
                const float4 ev = ep[j * 16 + f];
                s = fmaf(z4[j].x, ev.x, s); s = fmaf(z4[j].y, ev.y, s);
                s = fmaf(z4[j].z, ev.z, s); s = fmaf(z4[j].w, ev.w, s);
            }
#pragma unroll
            for (int off = 1; off < 16; off <<= 1) s += __shfl_xor(s, off, 64);
            const float d = fmaf(-2.0f, s, e2[col]);
            const unsigned long long key =
                ((unsigned long long)fkey(d) << 32) | (unsigned)col;
            if (key < pk) pk = key;
        }
#pragma unroll
        for (int off = 16; off < 64; off <<= 1) {
            const unsigned long long o = __shfl_xor(pk, off, 64);
            if (o < pk) pk = o;
        }
        if (lane == 0) atomicMin(&rowres[row], pk);
    }
}

// ---------------------------------------------------------------------------
// K6: gather z_q = en[idx], loss partials, indices (as float).
// ---------------------------------------------------------------------------
__global__ __launch_bounds__(256) void gather_out(const unsigned long long* __restrict__ rowres,
                                                  const float* __restrict__ en,
                                                  float* zqz,       // z_norm in / z_q out (d_out)
                                                  float* out_base,  // d_out
                                                  float* ws_loss) {
    const int lane = threadIdx.x & 63;
    const int row  = (blockIdx.x << 2) + (threadIdx.x >> 6);
    const int i = (int)(rowres[row] & 0xffffffffu);
    const float4 qv = *(const float4*)(en + i * DIM + lane * 4);
    const float4 zv = *(const float4*)(zqz + row * DIM + lane * 4);
    const float dx = qv.x - zv.x, dy = qv.y - zv.y, dz = qv.z - zv.z, dw = qv.w - zv.w;
    float s = dx * dx + dy * dy + dz * dz + dw * dw;
    *(float4*)(zqz + row * DIM + lane * 4) = qv;
#pragma unroll
    for (int off = 1; off < 64; off <<= 1) s += __shfl_xor(s, off, 64);
    if (lane == 0) {
        atomicAdd(ws_loss, s);
        out_base[N_TOK * DIM + 1 + row] = (float)i;
    }
}

__global__ void finalize_loss(const float* __restrict__ ws_loss, float* __restrict__ out) {
    out[N_TOK * DIM] = *ws_loss * (1.25f / 2097152.0f);
}

// ---------------------------------------------------------------------------
extern "C" void kernel_launch(void* const* d_in, const int* in_sizes, int n_in,
                              void* d_out, int out_size, void* d_ws, size_t ws_size,
                              hipStream_t stream) {
    const float* z   = (const float*)d_in[0];   // [8,1024,256] fp32
    const float* emb = (const float*)d_in[1];   // [8192,256] fp32
    float* out = (float*)d_out;                 // z_q[2097152] | loss[1] | idx[8192]
    char* ws = (char*)d_ws;

    // ws layout (byte offsets; total ~34.2 MB)
    float*              en     = (float*)(ws);                          //  8 MiB fp32 codes (normalized)
    unsigned short*     eb     = (unsigned short*)(ws + 8388608);       //  4 MiB bf16 codes
    unsigned short*     zb     = (unsigned short*)(ws + 12582912);      //  4 MiB bf16 z
    float*              e2     = (float*)(ws + 16777216);               // 32 KiB ||e||^2
    float*              segT   = (float*)(ws + 16809984);               // 16 MiB [512 segs][8192 rows]
    unsigned long long* rowres = (unsigned long long*)(ws + 33587200);  // 64 KiB packed results
    unsigned*           list   = (unsigned*)(ws + 33652736);            // 512 KiB rescore list
    int*                cnt    = (int*)(ws + 34177024);
    float*              wl     = (float*)(ws + 34177028);

    // 1) normalize embeddings -> en fp32 + eb bf16 + e2; zero wl/cnt
    l2norm_rows<<<N_E / 4, 256, 0, stream>>>(emb, en, eb, e2, wl, cnt);
    // 2) normalize z -> d_out z_q region (fp32 scratch) + zb bf16
    l2norm_rows<<<N_TOK / 4, 256, 0, stream>>>(z, out, zb, nullptr, nullptr, nullptr);
    // 3) bf16 MFMA approx distances -> per-(row, 16-col group) min, transposed
    mfma_dist<<<64 * 64, 256, 0, stream>>>(zb, eb, e2, segT);
    // 4) per-row merge + margin flags -> rescore list; init rowres
    merge_flag<<<N_TOK / 128, 256, 0, stream>>>(segT, rowres, list, cnt);
    // 5) exact fp32 rescore of flagged groups -> packed argmin per row
    rescore<<<1024, 256, 0, stream>>>(list, cnt, out, en, e2, rowres);
    // 6) gather z_q, loss partials, indices
    gather_out<<<N_TOK / 4, 256, 0, stream>>>(rowres, en, out, out, wl);
    // 7) scale loss
    finalize_loss<<<1, 1, 0, stream>>>(wl, out);
}

// Round 5
// 350.189 us; speedup vs baseline: 1.9857x; 1.3207x over previous
//
#include <hip/hip_runtime.h>
#include <cfloat>
#include <math.h>

// Problem constants (fixed by the reference)
#define DIM    256
#define N_TOK  8192
#define N_E    8192
#define NSEG   512          // 16-col groups per row
// Margin on d = ||e||^2 - 2*dot. Rigorous worst-case bf16 bound is 0.0312,
// but actual RNE error is a 512-term random sum: std(dd)~2e-4, max over 67M
// pairs ~1.1e-3. 0.016 = 7x the 2*max comparison requirement.
#define MARGIN 0.016f
#define CAP    131072       // rescore-list capacity (expected ~14k entries)

typedef __attribute__((ext_vector_type(8))) short bf16x8;
typedef __attribute__((ext_vector_type(4))) float f32x4;

__device__ __forceinline__ unsigned short f2bf(float f) {      // RNE float->bf16
    unsigned u = __float_as_uint(f);
    unsigned r = u + 0x7fff + ((u >> 16) & 1);
    return (unsigned short)(r >> 16);
}
__device__ __forceinline__ unsigned fkey(float f) {            // monotone f32->u32
    unsigned u = __float_as_uint(f);
    return (u & 0x80000000u) ? ~u : (u | 0x80000000u);
}

// ---------------------------------------------------------------------------
// K1/K2: row-wise L2 normalize -> fp32 out + bf16 out. Optionally ||out||^2
// per row and zeroing of the loss/cnt accumulators (ws is re-poisoned 0xAA).
// ---------------------------------------------------------------------------
__global__ __launch_bounds__(256) void l2norm_rows(const float* __restrict__ in,
                                                   float* __restrict__ out,
                                                   unsigned short* __restrict__ outb,
                                                   float* __restrict__ nsq,
                                                   float* __restrict__ zf,
                                                   int* __restrict__ zi) {
    if (zf && blockIdx.x == 0 && threadIdx.x == 0) { *zf = 0.0f; *zi = 0; }
    const int lane = threadIdx.x & 63;
    const int row  = (blockIdx.x << 2) + (threadIdx.x >> 6);
    const float4 v = *(const float4*)(in + row * DIM + lane * 4);
    float s = v.x * v.x + v.y * v.y + v.z * v.z + v.w * v.w;
#pragma unroll
    for (int off = 1; off < 64; off <<= 1) s += __shfl_xor(s, off, 64);
    const float inv = 1.0f / fmaxf(sqrtf(s), 1e-12f);
    const float4 o = make_float4(v.x * inv, v.y * inv, v.z * inv, v.w * inv);
    *(float4*)(out + row * DIM + lane * 4) = o;
    ushort4 ob; ob.x = f2bf(o.x); ob.y = f2bf(o.y); ob.z = f2bf(o.z); ob.w = f2bf(o.w);
    *(ushort4*)(outb + row * DIM + lane * 4) = ob;
    if (nsq) {
        float e2 = o.x * o.x + o.y * o.y + o.z * o.z + o.w * o.w;
#pragma unroll
        for (int off = 1; off < 64; off <<= 1) e2 += __shfl_xor(e2, off, 64);
        if (lane == 0) nsq[row] = e2;
    }
}

// ---------------------------------------------------------------------------
// K3: bf16 MFMA distance pass. 128x128 block tile, 4 waves of 64x64 (4x4 grid
// of 16x16x32 MFMAs), BK=32, global_load_lds width=16.
// OPERANDS SWAPPED vs the naive layout: A = codes, B = z rows, so the code
// dimension lands in the quad*4+reg axis of C/D. The per-(row, 16-code-group)
// min then needs only 3 in-register fminf + 2 cross-quad shuffles per (ci,zi)
// (32 ds_swizzles/wave vs 256 in the col-in-lane layout).
// Output written ROW-MAJOR segM[row][512] for the wave-per-row merge kernel.
// ---------------------------------------------------------------------------
__global__ __launch_bounds__(256, 2) void mfma_dist(const unsigned short* __restrict__ zb,
                                                    const unsigned short* __restrict__ eb,
                                                    const float* __restrict__ e2,
                                                    float* __restrict__ segM) {
    __shared__ __align__(16) unsigned short As[128][32];   // z rows  [row][k]
    __shared__ __align__(16) unsigned short Bs[128][32];   // codes   [col][k]
    __shared__ __align__(16) float sm[8][128];             // [seg_local][row_local]

    const int tid  = threadIdx.x;
    const int lane = tid & 63;
    const int wave = tid >> 6;
    const int wm = wave & 1, wn = wave >> 1;
    const int row0 = (blockIdx.x & 63) * 128;
    const int col0 = (blockIdx.x >> 6) * 128;

    f32x4 acc[4][4];
#pragma unroll
    for (int ci = 0; ci < 4; ci++)
#pragma unroll
        for (int zi = 0; zi < 4; zi++) acc[ci][zi] = (f32x4){0.f, 0.f, 0.f, 0.f};

    // Staging map: lane i -> row wave*32 + i/4, k-chunk (i%4)*8 (16B).
    const int srow  = lane >> 2;
    const int skoff = (lane & 3) * 8;
    const unsigned short* gA = zb + (row0 + wave * 32 + srow) * DIM + skoff;
    const unsigned short* gB = eb + (col0 + wave * 32 + srow) * DIM + skoff;

    for (int kc = 0; kc < DIM / 32; kc++) {
        __syncthreads();                       // readers of previous tile done
#pragma unroll
        for (int j = 0; j < 2; j++) {
            __builtin_amdgcn_global_load_lds(
                (const __attribute__((address_space(1))) unsigned int*)(gA + j * 16 * DIM + kc * 32),
                (__attribute__((address_space(3))) unsigned int*)&As[wave * 32 + j * 16][0],
                16, 0, 0);
            __builtin_amdgcn_global_load_lds(
                (const __attribute__((address_space(1))) unsigned int*)(gB + j * 16 * DIM + kc * 32),
                (__attribute__((address_space(3))) unsigned int*)&Bs[wave * 32 + j * 16][0],
                16, 0, 0);
        }
        __syncthreads();                       // staging drained (vmcnt(0) @ barrier)
        const int fr = lane & 15, q = lane >> 4;
        bf16x8 cf[4], zfr[4];
#pragma unroll
        for (int i = 0; i < 4; i++) cf[i]  = *(const bf16x8*)&Bs[wn * 64 + i * 16 + fr][q * 8];  // A = codes
#pragma unroll
        for (int i = 0; i < 4; i++) zfr[i] = *(const bf16x8*)&As[wm * 64 + i * 16 + fr][q * 8];  // B = z
#pragma unroll
        for (int ci = 0; ci < 4; ci++)
#pragma unroll
            for (int zi = 0; zi < 4; zi++)
                acc[ci][zi] = __builtin_amdgcn_mfma_f32_16x16x32_bf16(cf[ci], zfr[zi], acc[ci][zi], 0, 0, 0);
    }

    // Epilogue. C/D: m (code) = (lane>>4)*4 + reg, n (z row) = lane&15.
    const int fr = lane & 15, q = lane >> 4;
    float4 e2q[4];
#pragma unroll
    for (int ci = 0; ci < 4; ci++)
        e2q[ci] = *(const float4*)&e2[col0 + wn * 64 + ci * 16 + q * 4];
#pragma unroll
    for (int ci = 0; ci < 4; ci++) {
#pragma unroll
        for (int zi = 0; zi < 4; zi++) {
            const float t0 = fmaf(-2.0f, acc[ci][zi][0], e2q[ci].x);
            const float t1 = fmaf(-2.0f, acc[ci][zi][1], e2q[ci].y);
            const float t2 = fmaf(-2.0f, acc[ci][zi][2], e2q[ci].z);
            const float t3 = fmaf(-2.0f, acc[ci][zi][3], e2q[ci].w);
            float mm = fminf(fminf(t0, t1), fminf(t2, t3));   // min over 4 codes (regs)
            mm = fminf(mm, __shfl_xor(mm, 16, 64));           // min across quads
            mm = fminf(mm, __shfl_xor(mm, 32, 64));
            if (q == 0) sm[wn * 4 + ci][wm * 64 + zi * 16 + fr] = mm;
        }
    }
    __syncthreads();
    // Store 8 segs x 128 rows to row-major segM: thread t -> row t&127,
    // float4 over 4 consecutive segs (part = t>>7).
    {
        const int rl = tid & 127, part = tid >> 7;
        float4 v;
        v.x = sm[part * 4 + 0][rl]; v.y = sm[part * 4 + 1][rl];
        v.z = sm[part * 4 + 2][rl]; v.w = sm[part * 4 + 3][rl];
        *(float4*)&segM[(size_t)(row0 + rl) * NSEG + (col0 >> 4) + part * 4] = v;
    }
}

// ---------------------------------------------------------------------------
// K4: one WAVE per row (8192 waves): read 512 group-mins (2 KB contiguous),
// shuffle-min, flag groups within m+MARGIN (winner's group always
// self-flags), ballot-compact append to the rescore list.
// ---------------------------------------------------------------------------
__global__ __launch_bounds__(256) void merge_flag(const float* __restrict__ segM,
                                                  unsigned long long* __restrict__ rowres,
                                                  unsigned* __restrict__ list,
                                                  int* __restrict__ cnt) {
    const int lane = threadIdx.x & 63;
    const int row  = (blockIdx.x << 2) + (threadIdx.x >> 6);
    const float4* p = (const float4*)(segM + (size_t)row * NSEG);
    const float4 v0 = p[lane];        // segs 4*lane .. 4*lane+3
    const float4 v1 = p[64 + lane];   // segs 256+4*lane .. +3
    const float vv[8] = {v0.x, v0.y, v0.z, v0.w, v1.x, v1.y, v1.z, v1.w};
    float m = vv[0];
#pragma unroll
    for (int j = 1; j < 8; j++) m = fminf(m, vv[j]);
#pragma unroll
    for (int off = 1; off < 64; off <<= 1) m = fminf(m, __shfl_xor(m, off, 64));
    if (lane == 0) rowres[row] = ~0ull;
    const float thr = m + MARGIN;
    bool f[8];
    unsigned long long bal[8];
#pragma unroll
    for (int j = 0; j < 8; j++) { f[j] = vv[j] <= thr; bal[j] = __ballot(f[j]); }
    int total = 0;
#pragma unroll
    for (int j = 0; j < 8; j++) total += __popcll(bal[j]);
    int base = 0;
    if (lane == 0) base = atomicAdd(cnt, total);
    base = __shfl(base, 0, 64);
    const unsigned long long below = (1ull << lane) - 1;
    int off = 0;
#pragma unroll
    for (int j = 0; j < 8; j++) {
        if (f[j]) {
            const int pos = base + off + __popcll(bal[j] & below);
            const int seg = (j < 4) ? (lane * 4 + j) : (256 + lane * 4 + (j - 4));
            if (pos < CAP) list[pos] = (unsigned)((row << 9) | seg);
        }
        off += __popcll(bal[j]);
    }
}

// ---------------------------------------------------------------------------
// K5: exact fp32 rescore. One wave per (row, 16-col group): 4 passes of
// 4 cols; 16 lanes split the 256-dim fp32 dot (coalesced 1KB rows). Packed
// (sortable dist | col) u64 atomicMin per row -> exact argmin, lowest-index
// tie-break (matches jnp.argmin).
// ---------------------------------------------------------------------------
__global__ __launch_bounds__(256) void rescore(const unsigned* __restrict__ list,
                                               const int* __restrict__ cnt,
                                               const float* __restrict__ zn,
                                               const float* __restrict__ en,
                                               const float* __restrict__ e2,
                                               unsigned long long* __restrict__ rowres) {
    const int lane = threadIdx.x & 63;
    const int q = lane >> 4, f = lane & 15;
    const int w = (int)((blockIdx.x * blockDim.x + threadIdx.x) >> 6);
    const int W = (int)((gridDim.x * blockDim.x) >> 6);
    const int n = min(*cnt, (int)CAP);
    for (int i = w; i < n; i += W) {
        const unsigned ent = list[i];
        const int row = (int)(ent >> 9);
        const int seg = (int)(ent & 511u);
        const float4* zp = (const float4*)(zn + row * DIM);
        float4 z4[4];
#pragma unroll
        for (int j = 0; j < 4; j++) z4[j] = zp[j * 16 + f];
        unsigned long long pk = ~0ull;
#pragma unroll
        for (int g = 0; g < 4; g++) {
            const int col = seg * 16 + g * 4 + q;
            const float4* ep = (const float4*)(en + col * DIM);
            float s = 0.f;
#pragma unroll
            for (int j = 0; j < 4; j++) {
                const float4 ev = ep[j * 16 + f];
                s = fmaf(z4[j].x, ev.x, s); s = fmaf(z4[j].y, ev.y, s);
                s = fmaf(z4[j].z, ev.z, s); s = fmaf(z4[j].w, ev.w, s);
            }
#pragma unroll
            for (int off = 1; off < 16; off <<= 1) s += __shfl_xor(s, off, 64);
            const float d = fmaf(-2.0f, s, e2[col]);
            const unsigned long long key =
                ((unsigned long long)fkey(d) << 32) | (unsigned)col;
            if (key < pk) pk = key;
        }
#pragma unroll
        for (int off = 16; off < 64; off <<= 1) {
            const unsigned long long o = __shfl_xor(pk, off, 64);
            if (o < pk) pk = o;
        }
        if (lane == 0) atomicMin(&rowres[row], pk);
    }
}

// ---------------------------------------------------------------------------
// K6: gather z_q = en[idx], loss partials, indices (as float).
// ---------------------------------------------------------------------------
__global__ __launch_bounds__(256) void gather_out(const unsigned long long* __restrict__ rowres,
                                                  const float* __restrict__ en,
                                                  float* zqz,       // z_norm in / z_q out (d_out)
                                                  float* out_base,  // d_out
                                                  float* ws_loss) {
    const int lane = threadIdx.x & 63;
    const int row  = (blockIdx.x << 2) + (threadIdx.x >> 6);
    const int i = (int)(rowres[row] & 0xffffffffu);
    const float4 qv = *(const float4*)(en + i * DIM + lane * 4);
    const float4 zv = *(const float4*)(zqz + row * DIM + lane * 4);
    const float dx = qv.x - zv.x, dy = qv.y - zv.y, dz = qv.z - zv.z, dw = qv.w - zv.w;
    float s = dx * dx + dy * dy + dz * dz + dw * dw;
    *(float4*)(zqz + row * DIM + lane * 4) = qv;
#pragma unroll
    for (int off = 1; off < 64; off <<= 1) s += __shfl_xor(s, off, 64);
    if (lane == 0) {
        atomicAdd(ws_loss, s);
        out_base[N_TOK * DIM + 1 + row] = (float)i;
    }
}

__global__ void finalize_loss(const float* __restrict__ ws_loss, float* __restrict__ out) {
    out[N_TOK * DIM] = *ws_loss * (1.25f / 2097152.0f);
}

// ---------------------------------------------------------------------------
extern "C" void kernel_launch(void* const* d_in, const int* in_sizes, int n_in,
                              void* d_out, int out_size, void* d_ws, size_t ws_size,
                              hipStream_t stream) {
    const float* z   = (const float*)d_in[0];   // [8,1024,256] fp32
    const float* emb = (const float*)d_in[1];   // [8192,256] fp32
    float* out = (float*)d_out;                 // z_q[2097152] | loss[1] | idx[8192]
    char* ws = (char*)d_ws;

    // ws layout (byte offsets; total ~34.2 MB)
    float*              en     = (float*)(ws);                          //  8 MiB fp32 codes (normalized)
    unsigned short*     eb     = (unsigned short*)(ws + 8388608);       //  4 MiB bf16 codes
    unsigned short*     zb     = (unsigned short*)(ws + 12582912);      //  4 MiB bf16 z
    float*              e2     = (float*)(ws + 16777216);               // 32 KiB ||e||^2
    float*              segM   = (float*)(ws + 16809984);               // 16 MiB [8192 rows][512 segs]
    unsigned long long* rowres = (unsigned long long*)(ws + 33587200);  // 64 KiB packed results
    unsigned*           list   = (unsigned*)(ws + 33652736);            // 512 KiB rescore list
    int*                cnt    = (int*)(ws + 34177024);
    float*              wl     = (float*)(ws + 34177028);

    // 1) normalize embeddings -> en fp32 + eb bf16 + e2; zero wl/cnt
    l2norm_rows<<<N_E / 4, 256, 0, stream>>>(emb, en, eb, e2, wl, cnt);
    // 2) normalize z -> d_out z_q region (fp32 scratch) + zb bf16
    l2norm_rows<<<N_TOK / 4, 256, 0, stream>>>(z, out, zb, nullptr, nullptr, nullptr);
    // 3) bf16 MFMA approx distances -> per-(row, 16-col group) min, row-major
    mfma_dist<<<64 * 64, 256, 0, stream>>>(zb, eb, e2, segM);
    // 4) per-row merge + margin flags -> rescore list; init rowres
    merge_flag<<<N_TOK / 4, 256, 0, stream>>>(segM, rowres, list, cnt);
    // 5) exact fp32 rescore of flagged groups -> packed argmin per row
    rescore<<<1024, 256, 0, stream>>>(list, cnt, out, en, e2, rowres);
    // 6) gather z_q, loss partials, indices
    gather_out<<<N_TOK / 4, 256, 0, stream>>>(rowres, en, out, out, wl);
    // 7) scale loss
    finalize_loss<<<1, 1, 0, stream>>>(wl, out);
}

// Round 6
// 152.656 us; speedup vs baseline: 4.5551x; 2.2940x over previous
//
#include <hip/hip_runtime.h>
#include <cfloat>
#include <math.h>

// Problem constants (fixed by the reference)
#define DIM    256
#define N_TOK  8192
#define N_E    8192
#define NSEG   512          // 16-col groups per row
// Margin on d = ||e||^2 - 2*dot. Rigorous worst-case bf16 bound is 0.0312,
// but actual RNE error is a 512-term random sum: std(dd)~2e-4, max over 67M
// pairs ~1.1e-3. 0.016 = 7x the 2*max comparison requirement.
#define MARGIN 0.016f

typedef __attribute__((ext_vector_type(8))) short bf16x8;
typedef __attribute__((ext_vector_type(4))) float f32x4;

__device__ __forceinline__ unsigned short f2bf(float f) {      // RNE float->bf16
    unsigned u = __float_as_uint(f);
    unsigned r = u + 0x7fff + ((u >> 16) & 1);
    return (unsigned short)(r >> 16);
}
__device__ __forceinline__ unsigned fkey(float f) {            // monotone f32->u32
    unsigned u = __float_as_uint(f);
    return (u & 0x80000000u) ? ~u : (u | 0x80000000u);
}

// ---------------------------------------------------------------------------
// K1/K2: row-wise L2 normalize -> fp32 out + bf16 out. Optionally ||out||^2.
// ---------------------------------------------------------------------------
__global__ __launch_bounds__(256) void l2norm_rows(const float* __restrict__ in,
                                                   float* __restrict__ out,
                                                   unsigned short* __restrict__ outb,
                                                   float* __restrict__ nsq) {
    const int lane = threadIdx.x & 63;
    const int row  = (blockIdx.x << 2) + (threadIdx.x >> 6);
    const float4 v = *(const float4*)(in + row * DIM + lane * 4);
    float s = v.x * v.x + v.y * v.y + v.z * v.z + v.w * v.w;
#pragma unroll
    for (int off = 1; off < 64; off <<= 1) s += __shfl_xor(s, off, 64);
    const float inv = 1.0f / fmaxf(sqrtf(s), 1e-12f);
    const float4 o = make_float4(v.x * inv, v.y * inv, v.z * inv, v.w * inv);
    *(float4*)(out + row * DIM + lane * 4) = o;
    ushort4 ob; ob.x = f2bf(o.x); ob.y = f2bf(o.y); ob.z = f2bf(o.z); ob.w = f2bf(o.w);
    *(ushort4*)(outb + row * DIM + lane * 4) = ob;
    if (nsq) {
        float e2 = o.x * o.x + o.y * o.y + o.z * o.z + o.w * o.w;
#pragma unroll
        for (int off = 1; off < 64; off <<= 1) e2 += __shfl_xor(e2, off, 64);
        if (lane == 0) nsq[row] = e2;
    }
}

// ---------------------------------------------------------------------------
// K3: bf16 MFMA distance pass. 128x128 block tile, 4 waves of 64x64 (4x4 grid
// of 16x16x32 MFMAs), BK=32, global_load_lds width=16. A = codes, B = z rows
// (code dim lands in quad*4+reg of C/D -> cheap 16-col group min: 3 fminf +
// 2 cross-quad shuffles per (ci,zi)). Output row-major segM[row][512].
// ---------------------------------------------------------------------------
__global__ __launch_bounds__(256, 2) void mfma_dist(const unsigned short* __restrict__ zb,
                                                    const unsigned short* __restrict__ eb,
                                                    const float* __restrict__ e2,
                                                    float* __restrict__ segM) {
    __shared__ __align__(16) unsigned short As[128][32];   // z rows  [row][k]
    __shared__ __align__(16) unsigned short Bs[128][32];   // codes   [col][k]
    __shared__ __align__(16) float sm[8][128];             // [seg_local][row_local]

    const int tid  = threadIdx.x;
    const int lane = tid & 63;
    const int wave = tid >> 6;
    const int wm = wave & 1, wn = wave >> 1;
    const int row0 = (blockIdx.x & 63) * 128;
    const int col0 = (blockIdx.x >> 6) * 128;

    f32x4 acc[4][4];
#pragma unroll
    for (int ci = 0; ci < 4; ci++)
#pragma unroll
        for (int zi = 0; zi < 4; zi++) acc[ci][zi] = (f32x4){0.f, 0.f, 0.f, 0.f};

    // Staging map: lane i -> row wave*32 + i/4, k-chunk (i%4)*8 (16B).
    const int srow  = lane >> 2;
    const int skoff = (lane & 3) * 8;
    const unsigned short* gA = zb + (row0 + wave * 32 + srow) * DIM + skoff;
    const unsigned short* gB = eb + (col0 + wave * 32 + srow) * DIM + skoff;

    for (int kc = 0; kc < DIM / 32; kc++) {
        __syncthreads();                       // readers of previous tile done
#pragma unroll
        for (int j = 0; j < 2; j++) {
            __builtin_amdgcn_global_load_lds(
                (const __attribute__((address_space(1))) unsigned int*)(gA + j * 16 * DIM + kc * 32),
                (__attribute__((address_space(3))) unsigned int*)&As[wave * 32 + j * 16][0],
                16, 0, 0);
            __builtin_amdgcn_global_load_lds(
                (const __attribute__((address_space(1))) unsigned int*)(gB + j * 16 * DIM + kc * 32),
                (__attribute__((address_space(3))) unsigned int*)&Bs[wave * 32 + j * 16][0],
                16, 0, 0);
        }
        __syncthreads();                       // staging drained (vmcnt(0) @ barrier)
        const int fr = lane & 15, q = lane >> 4;
        bf16x8 cf[4], zfr[4];
#pragma unroll
        for (int i = 0; i < 4; i++) cf[i]  = *(const bf16x8*)&Bs[wn * 64 + i * 16 + fr][q * 8];  // A = codes
#pragma unroll
        for (int i = 0; i < 4; i++) zfr[i] = *(const bf16x8*)&As[wm * 64 + i * 16 + fr][q * 8];  // B = z
#pragma unroll
        for (int ci = 0; ci < 4; ci++)
#pragma unroll
            for (int zi = 0; zi < 4; zi++)
                acc[ci][zi] = __builtin_amdgcn_mfma_f32_16x16x32_bf16(cf[ci], zfr[zi], acc[ci][zi], 0, 0, 0);
    }

    // Epilogue. C/D: m (code) = (lane>>4)*4 + reg, n (z row) = lane&15.
    const int fr = lane & 15, q = lane >> 4;
    float4 e2q[4];
#pragma unroll
    for (int ci = 0; ci < 4; ci++)
        e2q[ci] = *(const float4*)&e2[col0 + wn * 64 + ci * 16 + q * 4];
#pragma unroll
    for (int ci = 0; ci < 4; ci++) {
#pragma unroll
        for (int zi = 0; zi < 4; zi++) {
            const float t0 = fmaf(-2.0f, acc[ci][zi][0], e2q[ci].x);
            const float t1 = fmaf(-2.0f, acc[ci][zi][1], e2q[ci].y);
            const float t2 = fmaf(-2.0f, acc[ci][zi][2], e2q[ci].z);
            const float t3 = fmaf(-2.0f, acc[ci][zi][3], e2q[ci].w);
            float mm = fminf(fminf(t0, t1), fminf(t2, t3));   // min over 4 codes (regs)
            mm = fminf(mm, __shfl_xor(mm, 16, 64));           // min across quads
            mm = fminf(mm, __shfl_xor(mm, 32, 64));
            if (q == 0) sm[wn * 4 + ci][wm * 64 + zi * 16 + fr] = mm;
        }
    }
    __syncthreads();
    // Store 8 segs x 128 rows to row-major segM: thread t -> row t&127,
    // float4 over 4 consecutive segs (part = t>>7).
    {
        const int rl = tid & 127, part = tid >> 7;
        float4 v;
        v.x = sm[part * 4 + 0][rl]; v.y = sm[part * 4 + 1][rl];
        v.z = sm[part * 4 + 2][rl]; v.w = sm[part * 4 + 3][rl];
        *(float4*)&segM[(size_t)(row0 + rl) * NSEG + (col0 >> 4) + part * 4] = v;
    }
}

// ---------------------------------------------------------------------------
// K4 (fused select+rescore+gather): one WAVE per row, ZERO atomics.
//  1. read 512 group-mins (2 KB contiguous), shuffle-min -> threshold
//  2. ballot-flag groups within m+MARGIN (winner's group always self-flags)
//  3. wave-uniform bit-walk over flagged groups; exact fp32 rescore (16 lanes
//     split the 256-dim dot, 4 cols at a time); packed (key|col) running min
//     -> exact argmin with lowest-index tie-break (matches jnp.argmin)
//  4. gather en[idx] -> z_q, per-row loss partial to pl[row], index out.
// ---------------------------------------------------------------------------
__global__ __launch_bounds__(256) void select_rescore(const float* __restrict__ segM,
                                                      const float* __restrict__ en,
                                                      const float* __restrict__ e2,
                                                      float* zq,        // d_out: z_norm in / z_q out
                                                      float* out_base,  // d_out
                                                      float* __restrict__ pl) {
    const int lane = threadIdx.x & 63;
    const int row  = (blockIdx.x << 2) + (threadIdx.x >> 6);
    const float4* p = (const float4*)(segM + (size_t)row * NSEG);
    const float4 v0 = p[lane];        // segs 4*lane .. 4*lane+3
    const float4 v1 = p[64 + lane];   // segs 256+4*lane .. +3
    const float vv[8] = {v0.x, v0.y, v0.z, v0.w, v1.x, v1.y, v1.z, v1.w};
    float m = vv[0];
#pragma unroll
    for (int j = 1; j < 8; j++) m = fminf(m, vv[j]);
#pragma unroll
    for (int off = 1; off < 64; off <<= 1) m = fminf(m, __shfl_xor(m, off, 64));
    const float thr = m + MARGIN;

    // z row in 16-lane-split layout for the rescore dots (shared by all groups)
    const int q = lane >> 4, f = lane & 15;
    const float4* zp = (const float4*)(zq + (size_t)row * DIM);
    float4 z4[4];
#pragma unroll
    for (int j = 0; j < 4; j++) z4[j] = zp[j * 16 + f];

    unsigned long long pk = ~0ull;
#pragma unroll
    for (int j = 0; j < 8; j++) {
        unsigned long long bal = __ballot(vv[j] <= thr);   // wave-uniform
        while (bal) {
            const int l = __ffsll(bal) - 1;
            bal &= bal - 1;
            const int seg = (j < 4) ? (l * 4 + j) : (256 + l * 4 + (j - 4));
#pragma unroll
            for (int g = 0; g < 4; g++) {
                const int col = seg * 16 + g * 4 + q;
                const float4* ep = (const float4*)(en + (size_t)col * DIM);
                float s = 0.f;
#pragma unroll
                for (int jj = 0; jj < 4; jj++) {
                    const float4 ev = ep[jj * 16 + f];
                    s = fmaf(z4[jj].x, ev.x, s); s = fmaf(z4[jj].y, ev.y, s);
                    s = fmaf(z4[jj].z, ev.z, s); s = fmaf(z4[jj].w, ev.w, s);
                }
#pragma unroll
                for (int off = 1; off < 16; off <<= 1) s += __shfl_xor(s, off, 64);
                const float d = fmaf(-2.0f, s, e2[col]);
                const unsigned long long key =
                    ((unsigned long long)fkey(d) << 32) | (unsigned)col;
                if (key < pk) pk = key;
            }
        }
    }
#pragma unroll
    for (int off = 16; off < 64; off <<= 1) {               // merge the 4 quads
        const unsigned long long o = __shfl_xor(pk, off, 64);
        if (o < pk) pk = o;
    }
    const int i = (int)(pk & 0xffffffffu);

    // Gather z_q, loss partial, index (plain stores, no atomics).
    const float4 qv = *(const float4*)(en + (size_t)i * DIM + lane * 4);
    const float4 zv = *(const float4*)(zq + (size_t)row * DIM + lane * 4);
    const float dx = qv.x - zv.x, dy = qv.y - zv.y, dz = qv.z - zv.z, dw = qv.w - zv.w;
    float s = dx * dx + dy * dy + dz * dz + dw * dw;
    *(float4*)(zq + (size_t)row * DIM + lane * 4) = qv;
#pragma unroll
    for (int off = 1; off < 64; off <<= 1) s += __shfl_xor(s, off, 64);
    if (lane == 0) {
        pl[row] = s;
        out_base[N_TOK * DIM + 1 + row] = (float)i;
    }
}

// ---------------------------------------------------------------------------
// K5: reduce 8192 per-row loss partials -> loss = 1.25 * sum / (8*1024*256).
// ---------------------------------------------------------------------------
__global__ __launch_bounds__(1024) void finalize_loss(const float* __restrict__ pl,
                                                      float* __restrict__ out) {
    __shared__ float sw[16];
    const int t = threadIdx.x;
    float s = 0.f;
#pragma unroll
    for (int j = 0; j < 8; j++) s += pl[t + j * 1024];
#pragma unroll
    for (int off = 1; off < 64; off <<= 1) s += __shfl_xor(s, off, 64);
    if ((t & 63) == 0) sw[t >> 6] = s;
    __syncthreads();
    if (t < 16) {
        float v = sw[t];
#pragma unroll
        for (int off = 1; off < 16; off <<= 1) v += __shfl_xor(v, off, 64);
        if (t == 0) out[N_TOK * DIM] = v * (1.25f / 2097152.0f);
    }
}

// ---------------------------------------------------------------------------
extern "C" void kernel_launch(void* const* d_in, const int* in_sizes, int n_in,
                              void* d_out, int out_size, void* d_ws, size_t ws_size,
                              hipStream_t stream) {
    const float* z   = (const float*)d_in[0];   // [8,1024,256] fp32
    const float* emb = (const float*)d_in[1];   // [8192,256] fp32
    float* out = (float*)d_out;                 // z_q[2097152] | loss[1] | idx[8192]
    char* ws = (char*)d_ws;

    // ws layout (byte offsets; total ~33.6 MB)
    float*          en   = (float*)(ws);                      //  8 MiB fp32 codes (normalized)
    unsigned short* eb   = (unsigned short*)(ws + 8388608);   //  4 MiB bf16 codes
    unsigned short* zb   = (unsigned short*)(ws + 12582912);  //  4 MiB bf16 z
    float*          e2   = (float*)(ws + 16777216);           // 32 KiB ||e||^2
    float*          segM = (float*)(ws + 16809984);           // 16 MiB [8192 rows][512 segs]
    float*          pl   = (float*)(ws + 33587200);           // 32 KiB per-row loss partials

    // 1) normalize embeddings -> en fp32 + eb bf16 + e2
    l2norm_rows<<<N_E / 4, 256, 0, stream>>>(emb, en, eb, e2);
    // 2) normalize z -> d_out z_q region (fp32 scratch) + zb bf16
    l2norm_rows<<<N_TOK / 4, 256, 0, stream>>>(z, out, zb, nullptr);
    // 3) bf16 MFMA approx distances -> per-(row, 16-col group) min, row-major
    mfma_dist<<<64 * 64, 256, 0, stream>>>(zb, eb, e2, segM);
    // 4) fused select + exact rescore + gather (wave per row, no atomics)
    select_rescore<<<N_TOK / 4, 256, 0, stream>>>(segM, en, e2, out, out, pl);
    // 5) reduce loss partials
    finalize_loss<<<1, 1024, 0, stream>>>(pl, out);
}

// Round 7
// 148.186 us; speedup vs baseline: 4.6925x; 1.0302x over previous
//
#include <hip/hip_runtime.h>
#include <cfloat>
#include <math.h>

// Problem constants (fixed by the reference)
#define DIM    256
#define N_TOK  8192
#define N_E    8192
#define NSEG   512          // 16-col groups per row
// Margin on d = ||e||^2 - 2*dot. Failure requires Dd(true winner)-Dd(approx
// winner) > margin on a specific per-row pair (16k pairs total): std ~4.8e-4,
// max ~4.3 sigma ~2.1e-3. 0.008 = 3.8x that. (0.016 passed with the same
// argmin as fp32 reference; halving trades headroom for ~2x fewer rescores.)
#define MARGIN 0.008f

typedef __attribute__((ext_vector_type(8))) short bf16x8;
typedef __attribute__((ext_vector_type(4))) float f32x4;

__device__ __forceinline__ unsigned short f2bf(float f) {      // RNE float->bf16
    unsigned u = __float_as_uint(f);
    unsigned r = u + 0x7fff + ((u >> 16) & 1);
    return (unsigned short)(r >> 16);
}
__device__ __forceinline__ unsigned fkey(float f) {            // monotone f32->u32
    unsigned u = __float_as_uint(f);
    return (u & 0x80000000u) ? ~u : (u | 0x80000000u);
}

// ---------------------------------------------------------------------------
// K1: row-wise L2 normalize for BOTH inputs in one launch (blocks 0..2047 =
// embeddings -> en/eb/e2; blocks 2048..4095 = z -> d_out/zb).
// ---------------------------------------------------------------------------
__global__ __launch_bounds__(256) void l2norm_all(const float* __restrict__ z,
                                                  const float* __restrict__ emb,
                                                  float* __restrict__ zn,
                                                  unsigned short* __restrict__ zb,
                                                  float* __restrict__ en,
                                                  unsigned short* __restrict__ eb,
                                                  float* __restrict__ e2) {
    const int lane = threadIdx.x & 63;
    const bool isE = blockIdx.x < (N_E / 4);
    const int row = (isE ? blockIdx.x : blockIdx.x - N_E / 4) * 4 + (threadIdx.x >> 6);
    const float* in = isE ? emb : z;
    float* out = isE ? en : zn;
    unsigned short* outb = isE ? eb : zb;
    const float4 v = *(const float4*)(in + row * DIM + lane * 4);
    float s = v.x * v.x + v.y * v.y + v.z * v.z + v.w * v.w;
#pragma unroll
    for (int off = 1; off < 64; off <<= 1) s += __shfl_xor(s, off, 64);
    const float inv = 1.0f / fmaxf(sqrtf(s), 1e-12f);
    const float4 o = make_float4(v.x * inv, v.y * inv, v.z * inv, v.w * inv);
    *(float4*)(out + row * DIM + lane * 4) = o;
    ushort4 ob; ob.x = f2bf(o.x); ob.y = f2bf(o.y); ob.z = f2bf(o.z); ob.w = f2bf(o.w);
    *(ushort4*)(outb + row * DIM + lane * 4) = ob;
    if (isE) {
        float q = o.x * o.x + o.y * o.y + o.z * o.z + o.w * o.w;
#pragma unroll
        for (int off = 1; off < 64; off <<= 1) q += __shfl_xor(q, off, 64);
        if (lane == 0) e2[row] = q;
    }
}

// ---------------------------------------------------------------------------
// K2: bf16 MFMA distance pass. 128x128 block tile, 4 waves of 64x64 (4x4 grid
// of 16x16x32 MFMAs), BK=32, global_load_lds width=16, SINGLE-BARRIER LDS
// double-buffer: stage chunk k+1 into the alternate buffer right after the
// barrier, compute chunk k — each barrier's vmcnt(0) drain then waits on
// loads that already had a full compute phase in flight.
// A = codes, B = z rows (code dim in quad*4+reg of C/D -> 16-col group min is
// 3 fminf + 2 cross-quad shuffles). Output row-major segM[row][512].
// ---------------------------------------------------------------------------
__global__ __launch_bounds__(256, 2) void mfma_dist(const unsigned short* __restrict__ zb,
                                                    const unsigned short* __restrict__ eb,
                                                    const float* __restrict__ e2,
                                                    float* __restrict__ segM) {
    __shared__ __align__(16) unsigned short As[2][128][32];   // z rows  [buf][row][k]
    __shared__ __align__(16) unsigned short Bs[2][128][32];   // codes   [buf][col][k]
    __shared__ __align__(16) float sm[8][128];                // [seg_local][row_local]

    const int tid  = threadIdx.x;
    const int lane = tid & 63;
    const int wave = tid >> 6;
    const int wm = wave & 1, wn = wave >> 1;
    const int row0 = (blockIdx.x & 63) * 128;
    const int col0 = (blockIdx.x >> 6) * 128;
    const int fr = lane & 15, q = lane >> 4;

    f32x4 acc[4][4];
#pragma unroll
    for (int ci = 0; ci < 4; ci++)
#pragma unroll
        for (int zi = 0; zi < 4; zi++) acc[ci][zi] = (f32x4){0.f, 0.f, 0.f, 0.f};

    // Staging map: lane i -> row wave*32 + i/4, k-chunk (i%4)*8 (16B).
    const int srow  = lane >> 2;
    const int skoff = (lane & 3) * 8;
    const unsigned short* gA = zb + (row0 + wave * 32 + srow) * DIM + skoff;
    const unsigned short* gB = eb + (col0 + wave * 32 + srow) * DIM + skoff;

    auto stage = [&](int buf, int kcn) {
#pragma unroll
        for (int j = 0; j < 2; j++) {
            __builtin_amdgcn_global_load_lds(
                (const __attribute__((address_space(1))) unsigned int*)(gA + j * 16 * DIM + kcn * 32),
                (__attribute__((address_space(3))) unsigned int*)&As[buf][wave * 32 + j * 16][0],
                16, 0, 0);
            __builtin_amdgcn_global_load_lds(
                (const __attribute__((address_space(1))) unsigned int*)(gB + j * 16 * DIM + kcn * 32),
                (__attribute__((address_space(3))) unsigned int*)&Bs[buf][wave * 32 + j * 16][0],
                16, 0, 0);
        }
    };
    auto compute = [&](int buf) {
        bf16x8 cf[4], zfr[4];
#pragma unroll
        for (int i = 0; i < 4; i++) cf[i]  = *(const bf16x8*)&Bs[buf][wn * 64 + i * 16 + fr][q * 8];
#pragma unroll
        for (int i = 0; i < 4; i++) zfr[i] = *(const bf16x8*)&As[buf][wm * 64 + i * 16 + fr][q * 8];
#pragma unroll
        for (int ci = 0; ci < 4; ci++)
#pragma unroll
            for (int zi = 0; zi < 4; zi++)
                acc[ci][zi] = __builtin_amdgcn_mfma_f32_16x16x32_bf16(cf[ci], zfr[zi], acc[ci][zi], 0, 0, 0);
    };

    stage(0, 0);
#pragma unroll
    for (int kc = 0; kc < 8; kc += 2) {
        __syncthreads();            // buf0 ready; all reads of buf1 drained
        stage(1, kc + 1);
        compute(0);
        __syncthreads();            // buf1 ready (loads had compute(0) in flight)
        if (kc + 2 < 8) stage(0, kc + 2);
        compute(1);
    }

    // Epilogue. C/D: m (code) = (lane>>4)*4 + reg, n (z row) = lane&15.
    float4 e2q[4];
#pragma unroll
    for (int ci = 0; ci < 4; ci++)
        e2q[ci] = *(const float4*)&e2[col0 + wn * 64 + ci * 16 + q * 4];
#pragma unroll
    for (int ci = 0; ci < 4; ci++) {
#pragma unroll
        for (int zi = 0; zi < 4; zi++) {
            const float t0 = fmaf(-2.0f, acc[ci][zi][0], e2q[ci].x);
            const float t1 = fmaf(-2.0f, acc[ci][zi][1], e2q[ci].y);
            const float t2 = fmaf(-2.0f, acc[ci][zi][2], e2q[ci].z);
            const float t3 = fmaf(-2.0f, acc[ci][zi][3], e2q[ci].w);
            float mm = fminf(fminf(t0, t1), fminf(t2, t3));   // min over 4 codes (regs)
            mm = fminf(mm, __shfl_xor(mm, 16, 64));           // min across quads
            mm = fminf(mm, __shfl_xor(mm, 32, 64));
            if (q == 0) sm[wn * 4 + ci][wm * 64 + zi * 16 + fr] = mm;
        }
    }
    __syncthreads();
    // Store 8 segs x 128 rows to row-major segM.
    {
        const int rl = tid & 127, part = tid >> 7;
        float4 v;
        v.x = sm[part * 4 + 0][rl]; v.y = sm[part * 4 + 1][rl];
        v.z = sm[part * 4 + 2][rl]; v.w = sm[part * 4 + 3][rl];
        *(float4*)&segM[(size_t)(row0 + rl) * NSEG + (col0 >> 4) + part * 4] = v;
    }
}

// ---------------------------------------------------------------------------
// K3 (fused select+rescore+gather): one WAVE per row, ZERO atomics.
// ---------------------------------------------------------------------------
__global__ __launch_bounds__(256) void select_rescore(const float* __restrict__ segM,
                                                      const float* __restrict__ en,
                                                      const float* __restrict__ e2,
                                                      float* zq,        // d_out: z_norm in / z_q out
                                                      float* out_base,  // d_out
                                                      float* __restrict__ pl) {
    const int lane = threadIdx.x & 63;
    const int row  = (blockIdx.x << 2) + (threadIdx.x >> 6);
    const float4* p = (const float4*)(segM + (size_t)row * NSEG);
    const float4 v0 = p[lane];        // segs 4*lane .. 4*lane+3
    const float4 v1 = p[64 + lane];   // segs 256+4*lane .. +3
    const float vv[8] = {v0.x, v0.y, v0.z, v0.w, v1.x, v1.y, v1.z, v1.w};
    float m = vv[0];
#pragma unroll
    for (int j = 1; j < 8; j++) m = fminf(m, vv[j]);
#pragma unroll
    for (int off = 1; off < 64; off <<= 1) m = fminf(m, __shfl_xor(m, off, 64));
    const float thr = m + MARGIN;

    // z row in 16-lane-split layout for the rescore dots (shared by all groups)
    const int q = lane >> 4, f = lane & 15;
    const float4* zp = (const float4*)(zq + (size_t)row * DIM);
    float4 z4[4];
#pragma unroll
    for (int j = 0; j < 4; j++) z4[j] = zp[j * 16 + f];

    unsigned long long pk = ~0ull;
#pragma unroll
    for (int j = 0; j < 8; j++) {
        unsigned long long bal = __ballot(vv[j] <= thr);   // wave-uniform
        while (bal) {
            const int l = __ffsll(bal) - 1;
            bal &= bal - 1;
            const int seg = (j < 4) ? (l * 4 + j) : (256 + l * 4 + (j - 4));
#pragma unroll
            for (int g = 0; g < 4; g++) {
                const int col = seg * 16 + g * 4 + q;
                const float4* ep = (const float4*)(en + (size_t)col * DIM);
                float s = 0.f;
#pragma unroll
                for (int jj = 0; jj < 4; jj++) {
                    const float4 ev = ep[jj * 16 + f];
                    s = fmaf(z4[jj].x, ev.x, s); s = fmaf(z4[jj].y, ev.y, s);
                    s = fmaf(z4[jj].z, ev.z, s); s = fmaf(z4[jj].w, ev.w, s);
                }
#pragma unroll
                for (int off = 1; off < 16; off <<= 1) s += __shfl_xor(s, off, 64);
                const float d = fmaf(-2.0f, s, e2[col]);
                const unsigned long long key =
                    ((unsigned long long)fkey(d) << 32) | (unsigned)col;
                if (key < pk) pk = key;
            }
        }
    }
#pragma unroll
    for (int off = 16; off < 64; off <<= 1) {               // merge the 4 quads
        const unsigned long long o = __shfl_xor(pk, off, 64);
        if (o < pk) pk = o;
    }
    const int i = (int)(pk & 0xffffffffu);

    // Gather z_q, loss partial, index (plain stores, no atomics).
    const float4 qv = *(const float4*)(en + (size_t)i * DIM + lane * 4);
    const float4 zv = *(const float4*)(zq + (size_t)row * DIM + lane * 4);
    const float dx = qv.x - zv.x, dy = qv.y - zv.y, dz = qv.z - zv.z, dw = qv.w - zv.w;
    float s = dx * dx + dy * dy + dz * dz + dw * dw;
    *(float4*)(zq + (size_t)row * DIM + lane * 4) = qv;
#pragma unroll
    for (int off = 1; off < 64; off <<= 1) s += __shfl_xor(s, off, 64);
    if (lane == 0) {
        pl[row] = s;
        out_base[N_TOK * DIM + 1 + row] = (float)i;
    }
}

// ---------------------------------------------------------------------------
// K4: reduce 8192 per-row loss partials -> loss = 1.25 * sum / (8*1024*256).
// ---------------------------------------------------------------------------
__global__ __launch_bounds__(1024) void finalize_loss(const float* __restrict__ pl,
                                                      float* __restrict__ out) {
    __shared__ float sw[16];
    const int t = threadIdx.x;
    float s = 0.f;
#pragma unroll
    for (int j = 0; j < 8; j++) s += pl[t + j * 1024];
#pragma unroll
    for (int off = 1; off < 64; off <<= 1) s += __shfl_xor(s, off, 64);
    if ((t & 63) == 0) sw[t >> 6] = s;
    __syncthreads();
    if (t < 16) {
        float v = sw[t];
#pragma unroll
        for (int off = 1; off < 16; off <<= 1) v += __shfl_xor(v, off, 64);
        if (t == 0) out[N_TOK * DIM] = v * (1.25f / 2097152.0f);
    }
}

// ---------------------------------------------------------------------------
extern "C" void kernel_launch(void* const* d_in, const int* in_sizes, int n_in,
                              void* d_out, int out_size, void* d_ws, size_t ws_size,
                              hipStream_t stream) {
    const float* z   = (const float*)d_in[0];   // [8,1024,256] fp32
    const float* emb = (const float*)d_in[1];   // [8192,256] fp32
    float* out = (float*)d_out;                 // z_q[2097152] | loss[1] | idx[8192]
    char* ws = (char*)d_ws;

    // ws layout (byte offsets; total ~33.6 MB)
    float*          en   = (float*)(ws);                      //  8 MiB fp32 codes (normalized)
    unsigned short* eb   = (unsigned short*)(ws + 8388608);   //  4 MiB bf16 codes
    unsigned short* zb   = (unsigned short*)(ws + 12582912);  //  4 MiB bf16 z
    float*          e2   = (float*)(ws + 16777216);           // 32 KiB ||e||^2
    float*          segM = (float*)(ws + 16809984);           // 16 MiB [8192 rows][512 segs]
    float*          pl   = (float*)(ws + 33587200);           // 32 KiB per-row loss partials

    // 1) normalize both inputs (emb -> en/eb/e2; z -> d_out z_q region + zb)
    l2norm_all<<<(N_E + N_TOK) / 4, 256, 0, stream>>>(z, emb, out, zb, en, eb, e2);
    // 2) bf16 MFMA approx distances -> per-(row, 16-col group) min, row-major
    mfma_dist<<<64 * 64, 256, 0, stream>>>(zb, eb, e2, segM);
    // 3) fused select + exact rescore + gather (wave per row, no atomics)
    select_rescore<<<N_TOK / 4, 256, 0, stream>>>(segM, en, e2, out, out, pl);
    // 4) reduce loss partials
    finalize_loss<<<1, 1024, 0, stream>>>(pl, out);
}